// Round 1
// baseline (783.720 us; speedup 1.0000x reference)
//
#include <hip/hip_runtime.h>
#include <hip/hip_bf16.h>

typedef __bf16 bf16_t;
typedef __attribute__((ext_vector_type(8))) __bf16 bf16x8;
typedef __attribute__((ext_vector_type(4))) float f32x4;

// ---------------------------------------------------------------------------
// global -> LDS direct copy, 16B per lane. LDS dest = uniform base + lane*16.
__device__ __forceinline__ void gload_lds16(const bf16_t* g, bf16_t* l) {
    __builtin_amdgcn_global_load_lds(
        (const __attribute__((address_space(1))) void*)g,
        (__attribute__((address_space(3))) void*)l,
        16, 0, 0);
}

// ---------------------------------------------------------------------------
// fp32 -> bf16 conversion (vectorized, 8 elems/thread)
__global__ void cvt_kernel(const float* __restrict__ in, bf16_t* __restrict__ out, int n) {
    int i = (blockIdx.x * blockDim.x + threadIdx.x) << 3;
    if (i >= n) return;
    const float4* p = (const float4*)(in + i);
    float4 a = p[0], b = p[1];
    bf16x8 o;
    o[0] = (bf16_t)a.x; o[1] = (bf16_t)a.y; o[2] = (bf16_t)a.z; o[3] = (bf16_t)a.w;
    o[4] = (bf16_t)b.x; o[5] = (bf16_t)b.y; o[6] = (bf16_t)b.z; o[7] = (bf16_t)b.w;
    *(bf16x8*)(out + i) = o;
}

// ---------------------------------------------------------------------------
// MXFP4 quantize w (K x N, fp32) -> dequantized bf16 stored TRANSPOSED (N x K).
// Per block of 32 along K: scale = 2^(floor(log2(amax)) - 2), E2M1 round-to-
// nearest with ties away from zero (matches jnp.digitize on midpoints).
// Dequant values q*2^e are exact in bf16.
__global__ void quantize_kernel(const float* __restrict__ w, bf16_t* __restrict__ wt,
                                int K, int N) {
    int tid = blockIdx.x * blockDim.x + threadIdx.x;
    int total = (K >> 5) * N;
    if (tid >= total) return;
    int n = tid % N;
    int b = tid / N;
    const float* src = w + (size_t)b * 32 * N + n;
    float v[32];
    float amax = 0.f;
#pragma unroll
    for (int i = 0; i < 32; ++i) {
        v[i] = src[(size_t)i * N];
        amax = fmaxf(amax, fabsf(v[i]));
    }
    unsigned eb = (__float_as_uint(amax) >> 23) & 0xFF;   // biased exponent
    float scale = __uint_as_float((eb - 2u) << 23);        // 2^(E-2)
    float inv   = __uint_as_float((256u - eb) << 23);      // 2^-(E-2)
    if (amax == 0.f) { scale = 0.f; inv = 0.f; }
    bf16_t dq[32];
#pragma unroll
    for (int i = 0; i < 32; ++i) {
        float x  = v[i] * inv;                             // exact (pow2 scale)
        float ax = fabsf(x);
        float q = ax < 0.25f ? 0.0f : ax < 0.75f ? 0.5f : ax < 1.25f ? 1.0f :
                  ax < 1.75f ? 1.5f : ax < 2.5f  ? 2.0f : ax < 3.5f  ? 3.0f :
                  ax < 5.0f  ? 4.0f : 6.0f;
        float d = copysignf(q * scale, x);
        dq[i] = (bf16_t)d;                                 // exact
    }
    bf16_t* dst = wt + (size_t)n * K + b * 32;
#pragma unroll
    for (int j = 0; j < 4; ++j) {
        bf16x8 p;
#pragma unroll
        for (int t = 0; t < 8; ++t) p[t] = dq[j * 8 + t];
        *(bf16x8*)(dst + j * 8) = p;
    }
}

// ---------------------------------------------------------------------------
// bf16 GEMM: C(MxN) = A(MxK) * B; B given as Bt (N x K).
// 128x128 tile, BK=64, 4 waves (2x2), each wave 64x64 = 4x4 frags of 16x16x32.
// global_load_lds width 16 with pre-swizzled global source; XOR-swizzled
// ds_read_b128 (conflict-free). EPI 0: gelu(v+bias) -> bf16. EPI 1: v+bias -> f32.
template <int EPI>
__global__ __launch_bounds__(256)
void gemm_kernel(const bf16_t* __restrict__ A, const bf16_t* __restrict__ Bt,
                 const float* __restrict__ bias, void* __restrict__ Cout,
                 int M, int N, int K) {
    __shared__ bf16_t sA[128 * 64];
    __shared__ bf16_t sB[128 * 64];
    const int tid  = threadIdx.x;
    const int lane = tid & 63;
    const int wv   = tid >> 6;
    const int wr   = wv >> 1, wc = wv & 1;

    // XCD-aware block swizzle (gridDim.x divisible by 8 for our shapes)
    const int ntn = N >> 7;
    const int nwg = gridDim.x;
    int bid = blockIdx.x;
    int wg  = (bid & 7) * (nwg >> 3) + (bid >> 3);
    const int bm = wg / ntn, bn = wg % ntn;

    // staging addressing: per instr a wave covers 8 rows x 64 cols (1KB)
    const int sr  = lane >> 3;           // row within 8-row group
    const int su  = lane & 7;            // 16B unit within row
    const int swz = ((su ^ sr) << 3);    // pre-swizzled global element offset
    const bf16_t* ag = A  + (size_t)(bm * 128 + wv * 32 + sr) * K + swz;
    const bf16_t* bg = Bt + (size_t)(bn * 128 + wv * 32 + sr) * K + swz;

    f32x4 acc[4][4];
#pragma unroll
    for (int i = 0; i < 4; ++i)
#pragma unroll
        for (int j = 0; j < 4; ++j) acc[i][j] = (f32x4){0.f, 0.f, 0.f, 0.f};

    for (int kt = 0; kt < K; kt += 64) {
        __syncthreads();
#pragma unroll
        for (int i = 0; i < 4; ++i) {
            gload_lds16(ag + kt + (size_t)(i * 8) * K, sA + (wv * 32 + i * 8) * 64);
            gload_lds16(bg + kt + (size_t)(i * 8) * K, sB + (wv * 32 + i * 8) * 64);
        }
        __syncthreads();

#pragma unroll
        for (int ks = 0; ks < 2; ++ks) {
            const int uw = (ks << 2) + (lane >> 4);   // k-unit 0..7
            bf16x8 af[4], bfr[4];
#pragma unroll
            for (int m = 0; m < 4; ++m) {
                int row = wr * 64 + m * 16 + (lane & 15);
                af[m] = *(const bf16x8*)(sA + row * 64 + ((uw ^ (row & 7)) << 3));
            }
#pragma unroll
            for (int n = 0; n < 4; ++n) {
                int row = wc * 64 + n * 16 + (lane & 15);
                bfr[n] = *(const bf16x8*)(sB + row * 64 + ((uw ^ (row & 7)) << 3));
            }
#pragma unroll
            for (int m = 0; m < 4; ++m)
#pragma unroll
                for (int n = 0; n < 4; ++n)
                    acc[m][n] = __builtin_amdgcn_mfma_f32_16x16x32_bf16(
                        af[m], bfr[n], acc[m][n], 0, 0, 0);
        }
    }

    // epilogue: C[row][col], col = lane&15, row = (lane>>4)*4 + j (per frag)
    const int r0 = bm * 128 + wr * 64 + ((lane >> 4) << 2);
    const int c0 = bn * 128 + wc * 64 + (lane & 15);
#pragma unroll
    for (int n = 0; n < 4; ++n) {
        int col  = c0 + n * 16;
        float bv = bias[col];
#pragma unroll
        for (int m = 0; m < 4; ++m) {
#pragma unroll
            for (int j = 0; j < 4; ++j) {
                int row = r0 + m * 16 + j;
                float v = acc[m][n][j] + bv;
                if (EPI == 0) {
                    float u = v + 0.044715f * v * v * v;
                    float t = tanhf(0.7978845608028654f * u);
                    float g = 0.5f * v * (1.f + t);
                    ((bf16_t*)Cout)[(size_t)row * N + col] = (bf16_t)g;
                } else {
                    ((float*)Cout)[(size_t)row * N + col] = v;
                }
            }
        }
    }
}

// ---------------------------------------------------------------------------
extern "C" void kernel_launch(void* const* d_in, const int* in_sizes, int n_in,
                              void* d_out, int out_size, void* d_ws, size_t ws_size,
                              hipStream_t stream) {
    const float* inputs = (const float*)d_in[0];
    const float* up_w   = (const float*)d_in[1];
    const float* up_b   = (const float*)d_in[2];
    const float* dn_w   = (const float*)d_in[3];
    const float* dn_b   = (const float*)d_in[4];
    float* out = (float*)d_out;

    const int D = in_sizes[4];            // 2048
    const int F = in_sizes[2];            // 8192
    const int M = in_sizes[0] / D;        // 8192 (B*S)

    // workspace layout (region0 reused: in_bf16 for GEMM1, then w_dn^T)
    size_t r0_bytes = (size_t)(M > F ? M : F) * D * 2;   // max(M*D, F*D) bf16
    char* ws = (char*)d_ws;
    bf16_t* in_bf = (bf16_t*)ws;                          // M x D
    bf16_t* wdn_t = (bf16_t*)ws;                          // D x F (after GEMM1)
    bf16_t* wup_t = (bf16_t*)(ws + r0_bytes);             // F x D
    bf16_t* mid   = (bf16_t*)(ws + r0_bytes + (size_t)F * D * 2);  // M x F

    // 1) inputs -> bf16
    int ncvt = M * D;
    cvt_kernel<<<(ncvt / 8 + 255) / 256, 256, 0, stream>>>(inputs, in_bf, ncvt);
    // 2) quantize+dequant up weights -> bf16, transposed (F x D)
    int qup = (D / 32) * F;
    quantize_kernel<<<(qup + 255) / 256, 256, 0, stream>>>(up_w, wup_t, D, F);
    // 3) GEMM1: mid = gelu(in @ W_up + b_up)   [M x F, bf16]
    gemm_kernel<0><<<(M / 128) * (F / 128), 256, 0, stream>>>(
        in_bf, wup_t, up_b, (void*)mid, M, F, D);
    // 4) quantize+dequant down weights -> bf16, transposed (D x F); reuses region0
    int qdn = (F / 32) * D;
    quantize_kernel<<<(qdn + 255) / 256, 256, 0, stream>>>(dn_w, wdn_t, F, D);
    // 5) GEMM2: out = mid @ W_dn + b_dn        [M x D, fp32]
    gemm_kernel<1><<<(M / 128) * (D / 128), 256, 0, stream>>>(
        mid, wdn_t, dn_b, (void*)out, M, D, F);
}

// Round 2
// 593.201 us; speedup vs baseline: 1.3212x; 1.3212x over previous
//
#include <hip/hip_runtime.h>
#include <hip/hip_bf16.h>

typedef __bf16 bf16_t;
typedef __attribute__((ext_vector_type(8))) __bf16 bf16x8;
typedef __attribute__((ext_vector_type(4))) float f32x4;

// ---------------------------------------------------------------------------
// global -> LDS direct copy, 16B per lane. LDS dest = wave-uniform base + lane*16.
__device__ __forceinline__ void gload_lds16(const bf16_t* g, bf16_t* l) {
    __builtin_amdgcn_global_load_lds(
        (const __attribute__((address_space(1))) void*)g,
        (__attribute__((address_space(3))) void*)l,
        16, 0, 0);
}

__device__ __forceinline__ float gelu_f(float v) {
    float u = 0.7978845608028654f * (v + 0.044715f * v * v * v);
    float e = __expf(-2.f * u);
    float t = __fdividef(1.f - e, 1.f + e);   // tanh(u), safe for |u| < 40
    return 0.5f * v * (1.f + t);
}

// ---------------------------------------------------------------------------
// fp32 -> bf16 conversion (vectorized, 8 elems/thread)
__global__ void cvt_kernel(const float* __restrict__ in, bf16_t* __restrict__ out, int n) {
    int i = (blockIdx.x * blockDim.x + threadIdx.x) << 3;
    if (i >= n) return;
    const float4* p = (const float4*)(in + i);
    float4 a = p[0], b = p[1];
    bf16x8 o;
    o[0] = (bf16_t)a.x; o[1] = (bf16_t)a.y; o[2] = (bf16_t)a.z; o[3] = (bf16_t)a.w;
    o[4] = (bf16_t)b.x; o[5] = (bf16_t)b.y; o[6] = (bf16_t)b.z; o[7] = (bf16_t)b.w;
    *(bf16x8*)(out + i) = o;
}

// ---------------------------------------------------------------------------
// MXFP4 quantize w (K x N, fp32) -> dequantized bf16 stored TRANSPOSED (N x K).
__global__ void quantize_kernel(const float* __restrict__ w, bf16_t* __restrict__ wt,
                                int K, int N) {
    int tid = blockIdx.x * blockDim.x + threadIdx.x;
    int total = (K >> 5) * N;
    if (tid >= total) return;
    int n = tid % N;
    int b = tid / N;
    const float* src = w + (size_t)b * 32 * N + n;
    float v[32];
    float amax = 0.f;
#pragma unroll
    for (int i = 0; i < 32; ++i) {
        v[i] = src[(size_t)i * N];
        amax = fmaxf(amax, fabsf(v[i]));
    }
    unsigned eb = (__float_as_uint(amax) >> 23) & 0xFF;   // biased exponent
    float scale = __uint_as_float((eb - 2u) << 23);        // 2^(E-2)
    float inv   = __uint_as_float((256u - eb) << 23);      // 2^-(E-2)
    if (amax == 0.f) { scale = 0.f; inv = 0.f; }
    bf16_t dq[32];
#pragma unroll
    for (int i = 0; i < 32; ++i) {
        float x  = v[i] * inv;                             // exact (pow2 scale)
        float ax = fabsf(x);
        float q = ax < 0.25f ? 0.0f : ax < 0.75f ? 0.5f : ax < 1.25f ? 1.0f :
                  ax < 1.75f ? 1.5f : ax < 2.5f  ? 2.0f : ax < 3.5f  ? 3.0f :
                  ax < 5.0f  ? 4.0f : 6.0f;
        float d = copysignf(q * scale, x);
        dq[i] = (bf16_t)d;                                 // exact
    }
    bf16_t* dst = wt + (size_t)n * K + b * 32;
#pragma unroll
    for (int j = 0; j < 4; ++j) {
        bf16x8 p;
#pragma unroll
        for (int t = 0; t < 8; ++t) p[t] = dq[j * 8 + t];
        *(bf16x8*)(dst + j * 8) = p;
    }
}

// ---------------------------------------------------------------------------
// 256x256x(BK=64) 8-phase bf16 GEMM (T1+T2+T3+T4+T5).
// 8 waves = 2M x 4N, per-wave C = 128x64. Double-buffered full K-tiles in LDS.
// Counted vmcnt(4) at phases 4/8 only; raw s_barriers; setprio around MFMA.
#define VMW4  asm volatile("s_waitcnt vmcnt(4)" ::: "memory")
#define VMW0  asm volatile("s_waitcnt vmcnt(0)" ::: "memory")
#define BARR  asm volatile("s_barrier" ::: "memory")
#define LGKM0 asm volatile("s_waitcnt lgkmcnt(0)" ::: "memory")

#define MFMA_ROW(MI, A0, A1)                                                          \
    acc[MI][0] = __builtin_amdgcn_mfma_f32_16x16x32_bf16(A0, bf00, acc[MI][0],0,0,0); \
    acc[MI][0] = __builtin_amdgcn_mfma_f32_16x16x32_bf16(A1, bf01, acc[MI][0],0,0,0); \
    acc[MI][1] = __builtin_amdgcn_mfma_f32_16x16x32_bf16(A0, bf10, acc[MI][1],0,0,0); \
    acc[MI][1] = __builtin_amdgcn_mfma_f32_16x16x32_bf16(A1, bf11, acc[MI][1],0,0,0); \
    acc[MI][2] = __builtin_amdgcn_mfma_f32_16x16x32_bf16(A0, bf20, acc[MI][2],0,0,0); \
    acc[MI][2] = __builtin_amdgcn_mfma_f32_16x16x32_bf16(A1, bf21, acc[MI][2],0,0,0); \
    acc[MI][3] = __builtin_amdgcn_mfma_f32_16x16x32_bf16(A0, bf30, acc[MI][3],0,0,0); \
    acc[MI][3] = __builtin_amdgcn_mfma_f32_16x16x32_bf16(A1, bf31, acc[MI][3],0,0,0);

#define PHASE(BUF, P, STAGE_STMT, TAIL_STMT)                                          \
  {                                                                                   \
    af00 = lda(BUF, 2*(P),   0); af01 = lda(BUF, 2*(P),   1);                         \
    af10 = lda(BUF, 2*(P)+1, 0); af11 = lda(BUF, 2*(P)+1, 1);                         \
    if ((P) == 0) {                                                                   \
      bf00 = ldb(BUF,0,0); bf01 = ldb(BUF,0,1);                                       \
      bf10 = ldb(BUF,1,0); bf11 = ldb(BUF,1,1);                                       \
      bf20 = ldb(BUF,2,0); bf21 = ldb(BUF,2,1);                                       \
      bf30 = ldb(BUF,3,0); bf31 = ldb(BUF,3,1);                                       \
    }                                                                                 \
    STAGE_STMT;                                                                       \
    BARR;                                                                             \
    LGKM0;                                                                            \
    __builtin_amdgcn_s_setprio(1);                                                    \
    MFMA_ROW(2*(P),   af00, af01);                                                    \
    MFMA_ROW(2*(P)+1, af10, af11);                                                    \
    __builtin_amdgcn_s_setprio(0);                                                    \
    TAIL_STMT;                                                                        \
    BARR;                                                                             \
  }

template <int EPI>
__global__ __launch_bounds__(512, 2)
void gemm_kernel(const bf16_t* __restrict__ A, const bf16_t* __restrict__ Bt,
                 const float* __restrict__ bias, void* __restrict__ Cout,
                 int M, int N, int K) {
    __shared__ bf16_t sA[2][256 * 64];
    __shared__ bf16_t sB[2][256 * 64];
    const int tid     = threadIdx.x;
    const int lane    = tid & 63;
    const int wv      = tid >> 6;          // 0..7
    const int wr      = wv >> 2;           // 0..1 (M)
    const int wc      = wv & 3;            // 0..3 (N)
    const int laneLow = lane & 15;
    const int laneHi  = lane >> 4;

    // XCD-aware block swizzle (nwg divisible by 8 for our shapes)
    const int ntn = N >> 8;
    const int nwg = gridDim.x;
    int bid = blockIdx.x;
    int wg  = (bid & 7) * (nwg >> 3) + (bid >> 3);
    const int bm = wg / ntn, bn = wg % ntn;

    // --- staging addressing: wave covers 8 rows x 64 cols (1 KB) per instr ---
    const int sr8 = lane >> 3;                 // row-within-8 (== row & 7)
    const int swz = (((lane & 7) ^ sr8) << 3); // pre-swizzled global col offset
    const bf16_t* aSrc = A  + (size_t)(bm * 256 + wv * 8 + sr8) * K + swz;
    const bf16_t* bSrc = Bt + (size_t)(bn * 256 + wv * 8 + sr8) * K + swz;

    auto stageA = [&](int b, int kt, int h) {
        const bf16_t* s = aSrc + (size_t)(h * 128) * K + kt * 64;
        gload_lds16(s,                &sA[b][(h * 128 + wv * 8) * 64]);
        gload_lds16(s + (size_t)64*K, &sA[b][(h * 128 + 64 + wv * 8) * 64]);
    };
    auto stageB = [&](int b, int kt, int h) {
        const bf16_t* s = bSrc + (size_t)(h * 128) * K + kt * 64;
        gload_lds16(s,                &sB[b][(h * 128 + wv * 8) * 64]);
        gload_lds16(s + (size_t)64*K, &sB[b][(h * 128 + 64 + wv * 8) * 64]);
    };

    // --- fragment reads (XOR-swizzled ds_read_b128, conflict-free) ---
    const int s7  = laneLow & 7;
    const int xk0 = ((laneHi) ^ s7) << 3;
    const int xk1 = ((4 + laneHi) ^ s7) << 3;
    const int aOffBase = (wr * 128 + laneLow) * 64;
    const int bOffBase = (wc * 64 + laneLow) * 64;
    auto lda = [&](int b, int m, int ks) -> bf16x8 {
        return *(const bf16x8*)(&sA[b][aOffBase + m * 1024 + (ks ? xk1 : xk0)]);
    };
    auto ldb = [&](int b, int n, int ks) -> bf16x8 {
        return *(const bf16x8*)(&sB[b][bOffBase + n * 1024 + (ks ? xk1 : xk0)]);
    };

    f32x4 acc[8][4];
#pragma unroll
    for (int i = 0; i < 8; ++i)
#pragma unroll
        for (int j = 0; j < 4; ++j) acc[i][j] = (f32x4){0.f, 0.f, 0.f, 0.f};

    bf16x8 af00, af01, af10, af11;
    bf16x8 bf00, bf01, bf10, bf11, bf20, bf21, bf30, bf31;

    // --- prologue: tile0 (buf0) fully, tile1 (buf1) B-halves ---
    stageA(0, 0, 0); stageA(0, 0, 1);
    stageB(0, 0, 0); stageB(0, 0, 1);
    stageB(1, 1, 0); stageB(1, 1, 1);
    VMW4;       // tile 0 fully landed; B(1) x2 halves still in flight
    BARR;

    const int niter = K >> 7;   // K/128, two K-tiles per iteration
    for (int i = 0; i < niter; ++i) {
        const bool nlast = (i + 1 < niter);
        const int kO  = 2 * i + 1;
        const int kN  = 2 * i + 2;
        const int kN1 = 2 * i + 3;
        // phases 1-4: compute buf0 (tile 2i)
        PHASE(0, 0, stageA(1, kO, 0), ((void)0));
        PHASE(0, 1, stageA(1, kO, 1), ((void)0));
        PHASE(0, 2, if (nlast) stageB(0, kN, 0), ((void)0));
        PHASE(0, 3, if (nlast) stageB(0, kN, 1),
              if (nlast) { VMW4; } else { VMW0; });
        // phases 5-8: compute buf1 (tile 2i+1)
        PHASE(1, 0, if (nlast) stageA(0, kN, 0), ((void)0));
        PHASE(1, 1, if (nlast) stageA(0, kN, 1), ((void)0));
        PHASE(1, 2, if (nlast) stageB(1, kN1, 0), ((void)0));
        PHASE(1, 3, if (nlast) stageB(1, kN1, 1),
              if (nlast) { VMW4; });
    }

    // --- epilogue: C[row][col], col = laneLow, row = laneHi*4 + j per frag ---
    const int r0 = bm * 256 + wr * 128 + (laneHi << 2);
    const int c0 = bn * 256 + wc * 64 + laneLow;
#pragma unroll
    for (int n = 0; n < 4; ++n) {
        const int col = c0 + n * 16;
        const float bv = bias[col];
#pragma unroll
        for (int m = 0; m < 8; ++m) {
#pragma unroll
            for (int j = 0; j < 4; ++j) {
                const int row = r0 + m * 16 + j;
                float v = acc[m][n][j] + bv;
                if (EPI == 0) {
                    ((bf16_t*)Cout)[(size_t)row * N + col] = (bf16_t)gelu_f(v);
                } else {
                    ((float*)Cout)[(size_t)row * N + col] = v;
                }
            }
        }
    }
}

// ---------------------------------------------------------------------------
extern "C" void kernel_launch(void* const* d_in, const int* in_sizes, int n_in,
                              void* d_out, int out_size, void* d_ws, size_t ws_size,
                              hipStream_t stream) {
    const float* inputs = (const float*)d_in[0];
    const float* up_w   = (const float*)d_in[1];
    const float* up_b   = (const float*)d_in[2];
    const float* dn_w   = (const float*)d_in[3];
    const float* dn_b   = (const float*)d_in[4];
    float* out = (float*)d_out;

    const int D = in_sizes[4];            // 2048
    const int F = in_sizes[2];            // 8192
    const int M = in_sizes[0] / D;        // 8192 (B*S)

    // workspace layout (region0 reused: in_bf16 for GEMM1, then w_dn^T)
    size_t r0_bytes = (size_t)(M > F ? M : F) * D * 2;
    char* ws = (char*)d_ws;
    bf16_t* in_bf = (bf16_t*)ws;                          // M x D
    bf16_t* wdn_t = (bf16_t*)ws;                          // D x F (after GEMM1)
    bf16_t* wup_t = (bf16_t*)(ws + r0_bytes);             // F x D
    bf16_t* mid   = (bf16_t*)(ws + r0_bytes + (size_t)F * D * 2);  // M x F

    // 1) inputs -> bf16
    int ncvt = M * D;
    cvt_kernel<<<(ncvt / 8 + 255) / 256, 256, 0, stream>>>(inputs, in_bf, ncvt);
    // 2) quantize+dequant up weights -> bf16, transposed (F x D)
    int qup = (D / 32) * F;
    quantize_kernel<<<(qup + 255) / 256, 256, 0, stream>>>(up_w, wup_t, D, F);
    // 3) GEMM1: mid = gelu(in @ W_up + b_up)   [M x F, bf16]
    gemm_kernel<0><<<(M / 256) * (F / 256), 512, 0, stream>>>(
        in_bf, wup_t, up_b, (void*)mid, M, F, D);
    // 4) quantize+dequant down weights -> bf16, transposed (D x F); reuses region0
    int qdn = (F / 32) * D;
    quantize_kernel<<<(qdn + 255) / 256, 256, 0, stream>>>(dn_w, wdn_t, F, D);
    // 5) GEMM2: out = mid @ W_dn + b_dn        [M x D, fp32]
    gemm_kernel<1><<<(M / 256) * (D / 256), 512, 0, stream>>>(
        mid, wdn_t, dn_b, (void*)out, M, D, F);
}

// Round 3
// 556.378 us; speedup vs baseline: 1.4086x; 1.0662x over previous
//
#include <hip/hip_runtime.h>
#include <hip/hip_bf16.h>

typedef __bf16 bf16_t;
typedef __attribute__((ext_vector_type(8))) __bf16 bf16x8;
typedef __attribute__((ext_vector_type(4))) float f32x4;

// ---------------------------------------------------------------------------
// global -> LDS direct copy, 16B per lane. LDS dest = wave-uniform base + lane*16.
__device__ __forceinline__ void gload_lds16(const bf16_t* g, bf16_t* l) {
    __builtin_amdgcn_global_load_lds(
        (const __attribute__((address_space(1))) void*)g,
        (__attribute__((address_space(3))) void*)l,
        16, 0, 0);
}

__device__ __forceinline__ float gelu_f(float v) {
    float u = 0.7978845608028654f * (v + 0.044715f * v * v * v);
    float e = __expf(-2.f * u);
    float t = __fdividef(1.f - e, 1.f + e);   // tanh(u)
    return 0.5f * v * (1.f + t);
}

// ---------------------------------------------------------------------------
// fp32 -> bf16 conversion (vectorized, 8 elems/thread)
__global__ void cvt_kernel(const float* __restrict__ in, bf16_t* __restrict__ out, int n) {
    int i = (blockIdx.x * blockDim.x + threadIdx.x) << 3;
    if (i >= n) return;
    const float4* p = (const float4*)(in + i);
    float4 a = p[0], b = p[1];
    bf16x8 o;
    o[0] = (bf16_t)a.x; o[1] = (bf16_t)a.y; o[2] = (bf16_t)a.z; o[3] = (bf16_t)a.w;
    o[4] = (bf16_t)b.x; o[5] = (bf16_t)b.y; o[6] = (bf16_t)b.z; o[7] = (bf16_t)b.w;
    *(bf16x8*)(out + i) = o;
}

// ---------------------------------------------------------------------------
// MXFP4 quantize w (K x N, fp32) -> dequantized bf16 stored TRANSPOSED (N x K).
__global__ void quantize_kernel(const float* __restrict__ w, bf16_t* __restrict__ wt,
                                int K, int N) {
    int tid = blockIdx.x * blockDim.x + threadIdx.x;
    int total = (K >> 5) * N;
    if (tid >= total) return;
    int n = tid % N;
    int b = tid / N;
    const float* src = w + (size_t)b * 32 * N + n;
    float v[32];
    float amax = 0.f;
#pragma unroll
    for (int i = 0; i < 32; ++i) {
        v[i] = src[(size_t)i * N];
        amax = fmaxf(amax, fabsf(v[i]));
    }
    unsigned eb = (__float_as_uint(amax) >> 23) & 0xFF;   // biased exponent
    float scale = __uint_as_float((eb - 2u) << 23);        // 2^(E-2)
    float inv   = __uint_as_float((256u - eb) << 23);      // 2^-(E-2)
    if (amax == 0.f) { scale = 0.f; inv = 0.f; }
    bf16_t dq[32];
#pragma unroll
    for (int i = 0; i < 32; ++i) {
        float x  = v[i] * inv;                             // exact (pow2 scale)
        float ax = fabsf(x);
        float q = ax < 0.25f ? 0.0f : ax < 0.75f ? 0.5f : ax < 1.25f ? 1.0f :
                  ax < 1.75f ? 1.5f : ax < 2.5f  ? 2.0f : ax < 3.5f  ? 3.0f :
                  ax < 5.0f  ? 4.0f : 6.0f;
        float d = copysignf(q * scale, x);
        dq[i] = (bf16_t)d;                                 // exact
    }
    bf16_t* dst = wt + (size_t)n * K + b * 32;
#pragma unroll
    for (int j = 0; j < 4; ++j) {
        bf16x8 p;
#pragma unroll
        for (int t = 0; t < 8; ++t) p[t] = dq[j * 8 + t];
        *(bf16x8*)(dst + j * 8) = p;
    }
}

// ---------------------------------------------------------------------------
// 256x256x(BK=64) 8-phase bf16 GEMM (T1+T2+T3+T4+T5).
// 8 waves = 2M x 4N, per-wave C = 128x64. Double-buffered full K-tiles in LDS.
// Counted vmcnt(4) at phases 4/8 only; raw s_barriers; setprio around MFMA.
// EPI 0: gelu+bias -> bf16 via LDS-staged coalesced stores (reuses sA/sB).
// EPI 1: bias -> f32 direct stores (64-B sectors, no RMW penalty).
#define VMW4  asm volatile("s_waitcnt vmcnt(4)" ::: "memory")
#define VMW0  asm volatile("s_waitcnt vmcnt(0)" ::: "memory")
#define BARR  asm volatile("s_barrier" ::: "memory")
#define LGKM0 asm volatile("s_waitcnt lgkmcnt(0)" ::: "memory")

#define MFMA_ROW(MI, A0, A1)                                                          \
    acc[MI][0] = __builtin_amdgcn_mfma_f32_16x16x32_bf16(A0, bf00, acc[MI][0],0,0,0); \
    acc[MI][0] = __builtin_amdgcn_mfma_f32_16x16x32_bf16(A1, bf01, acc[MI][0],0,0,0); \
    acc[MI][1] = __builtin_amdgcn_mfma_f32_16x16x32_bf16(A0, bf10, acc[MI][1],0,0,0); \
    acc[MI][1] = __builtin_amdgcn_mfma_f32_16x16x32_bf16(A1, bf11, acc[MI][1],0,0,0); \
    acc[MI][2] = __builtin_amdgcn_mfma_f32_16x16x32_bf16(A0, bf20, acc[MI][2],0,0,0); \
    acc[MI][2] = __builtin_amdgcn_mfma_f32_16x16x32_bf16(A1, bf21, acc[MI][2],0,0,0); \
    acc[MI][3] = __builtin_amdgcn_mfma_f32_16x16x32_bf16(A0, bf30, acc[MI][3],0,0,0); \
    acc[MI][3] = __builtin_amdgcn_mfma_f32_16x16x32_bf16(A1, bf31, acc[MI][3],0,0,0);

#define PHASE(BUF, P, STAGE_STMT, TAIL_STMT)                                          \
  {                                                                                   \
    af00 = lda(BUF, 2*(P),   0); af01 = lda(BUF, 2*(P),   1);                         \
    af10 = lda(BUF, 2*(P)+1, 0); af11 = lda(BUF, 2*(P)+1, 1);                         \
    if ((P) == 0) {                                                                   \
      bf00 = ldb(BUF,0,0); bf01 = ldb(BUF,0,1);                                       \
      bf10 = ldb(BUF,1,0); bf11 = ldb(BUF,1,1);                                       \
      bf20 = ldb(BUF,2,0); bf21 = ldb(BUF,2,1);                                       \
      bf30 = ldb(BUF,3,0); bf31 = ldb(BUF,3,1);                                       \
    }                                                                                 \
    STAGE_STMT;                                                                       \
    BARR;                                                                             \
    LGKM0;                                                                            \
    __builtin_amdgcn_s_setprio(1);                                                    \
    MFMA_ROW(2*(P),   af00, af01);                                                    \
    MFMA_ROW(2*(P)+1, af10, af11);                                                    \
    __builtin_amdgcn_s_setprio(0);                                                    \
    TAIL_STMT;                                                                        \
    BARR;                                                                             \
  }

template <int EPI>
__global__ __launch_bounds__(512, 2)
void gemm_kernel(const bf16_t* __restrict__ A, const bf16_t* __restrict__ Bt,
                 const float* __restrict__ bias, void* __restrict__ Cout,
                 int M, int N, int K) {
    __shared__ __align__(16) char smem[131072];
    bf16_t* sAp = (bf16_t*)smem;               // [2][256*64]
    bf16_t* sBp = (bf16_t*)(smem + 65536);     // [2][256*64]
    const int tid     = threadIdx.x;
    const int lane    = tid & 63;
    const int wv      = tid >> 6;          // 0..7
    const int wr      = wv >> 2;           // 0..1 (M)
    const int wc      = wv & 3;            // 0..3 (N)
    const int laneLow = lane & 15;
    const int laneHi  = lane >> 4;

    // XCD-aware block swizzle (nwg divisible by 8 for our shapes)
    const int ntn = N >> 8;
    const int nwg = gridDim.x;
    int bid = blockIdx.x;
    int wg  = (bid & 7) * (nwg >> 3) + (bid >> 3);
    const int bm = wg / ntn, bn = wg % ntn;

    // --- staging addressing: wave covers 8 rows x 64 cols (1 KB) per instr ---
    const int sr8 = lane >> 3;                 // row-within-8 (== row & 7)
    const int swz = (((lane & 7) ^ sr8) << 3); // pre-swizzled global col offset
    const bf16_t* aSrc = A  + (size_t)(bm * 256 + wv * 8 + sr8) * K + swz;
    const bf16_t* bSrc = Bt + (size_t)(bn * 256 + wv * 8 + sr8) * K + swz;

    auto stageA = [&](int b, int kt, int h) {
        const bf16_t* s = aSrc + (size_t)(h * 128) * K + kt * 64;
        gload_lds16(s,                &sAp[b * 16384 + (h * 128 + wv * 8) * 64]);
        gload_lds16(s + (size_t)64*K, &sAp[b * 16384 + (h * 128 + 64 + wv * 8) * 64]);
    };
    auto stageB = [&](int b, int kt, int h) {
        const bf16_t* s = bSrc + (size_t)(h * 128) * K + kt * 64;
        gload_lds16(s,                &sBp[b * 16384 + (h * 128 + wv * 8) * 64]);
        gload_lds16(s + (size_t)64*K, &sBp[b * 16384 + (h * 128 + 64 + wv * 8) * 64]);
    };

    // --- fragment reads (XOR-swizzled ds_read_b128, conflict-free) ---
    const int s7  = laneLow & 7;
    const int xk0 = ((laneHi) ^ s7) << 3;
    const int xk1 = ((4 + laneHi) ^ s7) << 3;
    const int aOffBase = (wr * 128 + laneLow) * 64;
    const int bOffBase = (wc * 64 + laneLow) * 64;
    auto lda = [&](int b, int m, int ks) -> bf16x8 {
        return *(const bf16x8*)(&sAp[b * 16384 + aOffBase + m * 1024 + (ks ? xk1 : xk0)]);
    };
    auto ldb = [&](int b, int n, int ks) -> bf16x8 {
        return *(const bf16x8*)(&sBp[b * 16384 + bOffBase + n * 1024 + (ks ? xk1 : xk0)]);
    };

    f32x4 acc[8][4];
#pragma unroll
    for (int i = 0; i < 8; ++i)
#pragma unroll
        for (int j = 0; j < 4; ++j) acc[i][j] = (f32x4){0.f, 0.f, 0.f, 0.f};

    bf16x8 af00, af01, af10, af11;
    bf16x8 bf00, bf01, bf10, bf11, bf20, bf21, bf30, bf31;

    // --- prologue: tile0 (buf0) fully, tile1 (buf1) B-halves ---
    stageA(0, 0, 0); stageA(0, 0, 1);
    stageB(0, 0, 0); stageB(0, 0, 1);
    stageB(1, 1, 0); stageB(1, 1, 1);
    VMW4;       // tile 0 fully landed; B(1) x2 halves still in flight
    BARR;

    const int niter = K >> 7;   // K/128, two K-tiles per iteration
    for (int i = 0; i < niter; ++i) {
        const bool nlast = (i + 1 < niter);
        const int kO  = 2 * i + 1;
        const int kN  = 2 * i + 2;
        const int kN1 = 2 * i + 3;
        // phases 1-4: compute buf0 (tile 2i)
        PHASE(0, 0, stageA(1, kO, 0), ((void)0));
        PHASE(0, 1, stageA(1, kO, 1), ((void)0));
        PHASE(0, 2, if (nlast) stageB(0, kN, 0), ((void)0));
        PHASE(0, 3, if (nlast) stageB(0, kN, 1),
              if (nlast) { VMW4; } else { VMW0; });
        // phases 5-8: compute buf1 (tile 2i+1)
        PHASE(1, 0, if (nlast) stageA(0, kN, 0), ((void)0));
        PHASE(1, 1, if (nlast) stageA(0, kN, 1), ((void)0));
        PHASE(1, 2, if (nlast) stageB(1, kN1, 0), ((void)0));
        PHASE(1, 3, if (nlast) stageB(1, kN1, 1),
              if (nlast) { VMW4; });
    }

    if (EPI == 0) {
        // --- LDS-staged coalesced bf16 epilogue (gelu). sA/sB dead after the
        // final phase barrier; reuse the 128 KiB as sC[256][256] bf16 with a
        // bank XOR-swizzle (bits [6:5] ^= row>>2) so fragment writes are
        // conflict-free and read-back is linear.
        bf16_t* sC = (bf16_t*)smem;
#pragma unroll
        for (int n = 0; n < 4; ++n) {
            const int colL = wc * 64 + n * 16 + laneLow;
            const float bv = bias[bn * 256 + colL];
#pragma unroll
            for (int m = 0; m < 8; ++m) {
#pragma unroll
                for (int j = 0; j < 4; ++j) {
                    const int rowL = wr * 128 + m * 16 + (laneHi << 2) + j;
                    float v = acc[m][n][j] + bv;
                    int byte = (rowL << 9) + (colL << 1);
                    byte ^= ((rowL >> 2) & 3) << 5;
                    *(bf16_t*)((char*)sC + byte) = (bf16_t)gelu_f(v);
                }
            }
        }
        LGKM0;
        BARR;
        bf16_t* Cb = (bf16_t*)Cout;
        const size_t rb = (size_t)bm * 256, cb = (size_t)bn * 256;
#pragma unroll
        for (int s = 0; s < 16; ++s) {
            const int row = s * 16 + (tid >> 5);
            int byte = (row << 9) + ((tid & 31) << 4);
            byte ^= ((row >> 2) & 3) << 5;
            bf16x8 v = *(const bf16x8*)((char*)sC + byte);
            *(bf16x8*)(&Cb[(rb + row) * N + cb + ((tid & 31) << 3)]) = v;
        }
    } else {
        // --- direct f32 epilogue (64-B contiguous sectors per quarter-wave) ---
        const int r0 = bm * 256 + wr * 128 + (laneHi << 2);
        const int c0 = bn * 256 + wc * 64 + laneLow;
        float* Cf = (float*)Cout;
#pragma unroll
        for (int n = 0; n < 4; ++n) {
            const int col = c0 + n * 16;
            const float bv = bias[col];
#pragma unroll
            for (int m = 0; m < 8; ++m) {
#pragma unroll
                for (int j = 0; j < 4; ++j) {
                    const int row = r0 + m * 16 + j;
                    Cf[(size_t)row * N + col] = acc[m][n][j] + bv;
                }
            }
        }
    }
}

// ---------------------------------------------------------------------------
extern "C" void kernel_launch(void* const* d_in, const int* in_sizes, int n_in,
                              void* d_out, int out_size, void* d_ws, size_t ws_size,
                              hipStream_t stream) {
    const float* inputs = (const float*)d_in[0];
    const float* up_w   = (const float*)d_in[1];
    const float* up_b   = (const float*)d_in[2];
    const float* dn_w   = (const float*)d_in[3];
    const float* dn_b   = (const float*)d_in[4];
    float* out = (float*)d_out;

    const int D = in_sizes[4];            // 2048
    const int F = in_sizes[2];            // 8192
    const int M = in_sizes[0] / D;        // 8192 (B*S)

    // workspace layout (region0 reused: in_bf16 for GEMM1, then w_dn^T)
    size_t r0_bytes = (size_t)(M > F ? M : F) * D * 2;
    char* ws = (char*)d_ws;
    bf16_t* in_bf = (bf16_t*)ws;                          // M x D
    bf16_t* wdn_t = (bf16_t*)ws;                          // D x F (after GEMM1)
    bf16_t* wup_t = (bf16_t*)(ws + r0_bytes);             // F x D
    bf16_t* mid   = (bf16_t*)(ws + r0_bytes + (size_t)F * D * 2);  // M x F

    // 1) inputs -> bf16
    int ncvt = M * D;
    cvt_kernel<<<(ncvt / 8 + 255) / 256, 256, 0, stream>>>(inputs, in_bf, ncvt);
    // 2) quantize+dequant up weights -> bf16, transposed (F x D)
    int qup = (D / 32) * F;
    quantize_kernel<<<(qup + 255) / 256, 256, 0, stream>>>(up_w, wup_t, D, F);
    // 3) GEMM1: mid = gelu(in @ W_up + b_up)   [M x F, bf16]
    gemm_kernel<0><<<(M / 256) * (F / 256), 512, 0, stream>>>(
        in_bf, wup_t, up_b, (void*)mid, M, F, D);
    // 4) quantize+dequant down weights -> bf16, transposed (D x F); reuses region0
    int qdn = (F / 32) * D;
    quantize_kernel<<<(qdn + 255) / 256, 256, 0, stream>>>(dn_w, wdn_t, F, D);
    // 5) GEMM2: out = mid @ W_dn + b_dn        [M x D, fp32]
    gemm_kernel<1><<<(M / 256) * (D / 256), 512, 0, stream>>>(
        mid, wdn_t, dn_b, (void*)out, M, D, F);
}

// Round 4
// 544.523 us; speedup vs baseline: 1.4393x; 1.0218x over previous
//
#include <hip/hip_runtime.h>
#include <hip/hip_bf16.h>

typedef __bf16 bf16_t;
typedef __attribute__((ext_vector_type(8))) __bf16 bf16x8;
typedef __attribute__((ext_vector_type(4))) float f32x4;

// ---------------------------------------------------------------------------
// global -> LDS direct copy, 16B per lane. LDS dest = wave-uniform base + lane*16.
__device__ __forceinline__ void gload_lds16(const bf16_t* g, bf16_t* l) {
    __builtin_amdgcn_global_load_lds(
        (const __attribute__((address_space(1))) void*)g,
        (__attribute__((address_space(3))) void*)l,
        16, 0, 0);
}

__device__ __forceinline__ float gelu_f(float v) {
    float u = 0.7978845608028654f * (v + 0.044715f * v * v * v);
    float e = __expf(-2.f * u);
    float t = __fdividef(1.f - e, 1.f + e);   // tanh(u)
    return 0.5f * v * (1.f + t);
}

// ---------------------------------------------------------------------------
// fp32 -> bf16 conversion (vectorized, 8 elems/thread)
__global__ void cvt_kernel(const float* __restrict__ in, bf16_t* __restrict__ out, int n) {
    int i = (blockIdx.x * blockDim.x + threadIdx.x) << 3;
    if (i >= n) return;
    const float4* p = (const float4*)(in + i);
    float4 a = p[0], b = p[1];
    bf16x8 o;
    o[0] = (bf16_t)a.x; o[1] = (bf16_t)a.y; o[2] = (bf16_t)a.z; o[3] = (bf16_t)a.w;
    o[4] = (bf16_t)b.x; o[5] = (bf16_t)b.y; o[6] = (bf16_t)b.z; o[7] = (bf16_t)b.w;
    *(bf16x8*)(out + i) = o;
}

// ---------------------------------------------------------------------------
// MXFP4 quantize w (K x N, fp32) -> dequantized bf16 stored TRANSPOSED (N x K).
__global__ void quantize_kernel(const float* __restrict__ w, bf16_t* __restrict__ wt,
                                int K, int N) {
    int tid = blockIdx.x * blockDim.x + threadIdx.x;
    int total = (K >> 5) * N;
    if (tid >= total) return;
    int n = tid % N;
    int b = tid / N;
    const float* src = w + (size_t)b * 32 * N + n;
    float v[32];
    float amax = 0.f;
#pragma unroll
    for (int i = 0; i < 32; ++i) {
        v[i] = src[(size_t)i * N];
        amax = fmaxf(amax, fabsf(v[i]));
    }
    unsigned eb = (__float_as_uint(amax) >> 23) & 0xFF;   // biased exponent
    float scale = __uint_as_float((eb - 2u) << 23);        // 2^(E-2)
    float inv   = __uint_as_float((256u - eb) << 23);      // 2^-(E-2)
    if (amax == 0.f) { scale = 0.f; inv = 0.f; }
    bf16_t dq[32];
#pragma unroll
    for (int i = 0; i < 32; ++i) {
        float x  = v[i] * inv;                             // exact (pow2 scale)
        float ax = fabsf(x);
        float q = ax < 0.25f ? 0.0f : ax < 0.75f ? 0.5f : ax < 1.25f ? 1.0f :
                  ax < 1.75f ? 1.5f : ax < 2.5f  ? 2.0f : ax < 3.5f  ? 3.0f :
                  ax < 5.0f  ? 4.0f : 6.0f;
        float d = copysignf(q * scale, x);
        dq[i] = (bf16_t)d;                                 // exact
    }
    bf16_t* dst = wt + (size_t)n * K + b * 32;
#pragma unroll
    for (int j = 0; j < 4; ++j) {
        bf16x8 p;
#pragma unroll
        for (int t = 0; t < 8; ++t) p[t] = dq[j * 8 + t];
        *(bf16x8*)(dst + j * 8) = p;
    }
}

// ---------------------------------------------------------------------------
// 256x256x(BK=64) 8-phase bf16 GEMM (T1+T2+T3+T4+T5).
// 8 waves = 2M x 4N, per-wave C = 128x64. Double-buffered full K-tiles in LDS.
// Counted vmcnt(4) at phases 4/8 only; raw s_barriers; setprio around MFMA.
// MAP 0: chunked XCD swizzle. MAP 1: hierarchical 4bm x 8bn per-XCD supertile
//        (for 32x32-tile grids) -- shrinks per-XCD L2 working set per round
//        from 34.5 MB (1bm x 32bn slab) to 12.6 MB.
#define VMW4  asm volatile("s_waitcnt vmcnt(4)" ::: "memory")
#define VMW0  asm volatile("s_waitcnt vmcnt(0)" ::: "memory")
#define BARR  asm volatile("s_barrier" ::: "memory")
#define LGKM0 asm volatile("s_waitcnt lgkmcnt(0)" ::: "memory")

#define MFMA_ROW(MI, A0, A1)                                                          \
    acc[MI][0] = __builtin_amdgcn_mfma_f32_16x16x32_bf16(A0, bf00, acc[MI][0],0,0,0); \
    acc[MI][0] = __builtin_amdgcn_mfma_f32_16x16x32_bf16(A1, bf01, acc[MI][0],0,0,0); \
    acc[MI][1] = __builtin_amdgcn_mfma_f32_16x16x32_bf16(A0, bf10, acc[MI][1],0,0,0); \
    acc[MI][1] = __builtin_amdgcn_mfma_f32_16x16x32_bf16(A1, bf11, acc[MI][1],0,0,0); \
    acc[MI][2] = __builtin_amdgcn_mfma_f32_16x16x32_bf16(A0, bf20, acc[MI][2],0,0,0); \
    acc[MI][2] = __builtin_amdgcn_mfma_f32_16x16x32_bf16(A1, bf21, acc[MI][2],0,0,0); \
    acc[MI][3] = __builtin_amdgcn_mfma_f32_16x16x32_bf16(A0, bf30, acc[MI][3],0,0,0); \
    acc[MI][3] = __builtin_amdgcn_mfma_f32_16x16x32_bf16(A1, bf31, acc[MI][3],0,0,0);

#define PHASE(BUF, P, STAGE_STMT, TAIL_STMT)                                          \
  {                                                                                   \
    af00 = lda(BUF, 2*(P),   0); af01 = lda(BUF, 2*(P),   1);                         \
    af10 = lda(BUF, 2*(P)+1, 0); af11 = lda(BUF, 2*(P)+1, 1);                         \
    if ((P) == 0) {                                                                   \
      bf00 = ldb(BUF,0,0); bf01 = ldb(BUF,0,1);                                       \
      bf10 = ldb(BUF,1,0); bf11 = ldb(BUF,1,1);                                       \
      bf20 = ldb(BUF,2,0); bf21 = ldb(BUF,2,1);                                       \
      bf30 = ldb(BUF,3,0); bf31 = ldb(BUF,3,1);                                       \
    }                                                                                 \
    STAGE_STMT;                                                                       \
    BARR;                                                                             \
    LGKM0;                                                                            \
    __builtin_amdgcn_s_setprio(1);                                                    \
    MFMA_ROW(2*(P),   af00, af01);                                                    \
    MFMA_ROW(2*(P)+1, af10, af11);                                                    \
    __builtin_amdgcn_s_setprio(0);                                                    \
    TAIL_STMT;                                                                        \
    BARR;                                                                             \
  }

template <int EPI, int MAP>
__global__ __launch_bounds__(512, 2)
void gemm_kernel(const bf16_t* __restrict__ A, const bf16_t* __restrict__ Bt,
                 const float* __restrict__ bias, void* __restrict__ Cout,
                 int M, int N, int K) {
    __shared__ __align__(16) char smem[131072];
    bf16_t* sAp = (bf16_t*)smem;               // [2][256*64]
    bf16_t* sBp = (bf16_t*)(smem + 65536);     // [2][256*64]
    const int tid     = threadIdx.x;
    const int lane    = tid & 63;
    const int wv      = tid >> 6;          // 0..7
    const int wr      = wv >> 2;           // 0..1 (M)
    const int wc      = wv & 3;            // 0..3 (N)
    const int laneLow = lane & 15;
    const int laneHi  = lane >> 4;

    int bm, bn;
    const int bid = blockIdx.x;
    if (MAP == 1) {
        // hierarchical: per-XCD concurrent window = 4bm x 8bn supertile.
        // bid&7 = XCD; l = in-XCD sequence; r = round (32 blocks/XCD/round).
        const int xcd = bid & 7;
        const int l   = bid >> 3;
        const int r   = l >> 5;
        const int u   = l & 31;
        bm = r * 8 + ((xcd >> 2) << 2) + (u >> 3);
        bn = ((xcd & 3) << 3) + (u & 7);
    } else {
        const int ntn = N >> 8;
        const int nwg = gridDim.x;
        int wg  = (bid & 7) * (nwg >> 3) + (bid >> 3);
        bm = wg / ntn; bn = wg % ntn;
    }

    // --- staging addressing: wave covers 8 rows x 64 cols (1 KB) per instr ---
    const int sr8 = lane >> 3;                 // row-within-8 (== row & 7)
    const int swz = (((lane & 7) ^ sr8) << 3); // pre-swizzled global col offset
    const bf16_t* aSrc = A  + (size_t)(bm * 256 + wv * 8 + sr8) * K + swz;
    const bf16_t* bSrc = Bt + (size_t)(bn * 256 + wv * 8 + sr8) * K + swz;

    auto stageA = [&](int b, int kt, int h) {
        const bf16_t* s = aSrc + (size_t)(h * 128) * K + kt * 64;
        gload_lds16(s,                &sAp[b * 16384 + (h * 128 + wv * 8) * 64]);
        gload_lds16(s + (size_t)64*K, &sAp[b * 16384 + (h * 128 + 64 + wv * 8) * 64]);
    };
    auto stageB = [&](int b, int kt, int h) {
        const bf16_t* s = bSrc + (size_t)(h * 128) * K + kt * 64;
        gload_lds16(s,                &sBp[b * 16384 + (h * 128 + wv * 8) * 64]);
        gload_lds16(s + (size_t)64*K, &sBp[b * 16384 + (h * 128 + 64 + wv * 8) * 64]);
    };

    // --- fragment reads (XOR-swizzled ds_read_b128, conflict-free) ---
    const int s7  = laneLow & 7;
    const int xk0 = ((laneHi) ^ s7) << 3;
    const int xk1 = ((4 + laneHi) ^ s7) << 3;
    const int aOffBase = (wr * 128 + laneLow) * 64;
    const int bOffBase = (wc * 64 + laneLow) * 64;
    auto lda = [&](int b, int m, int ks) -> bf16x8 {
        return *(const bf16x8*)(&sAp[b * 16384 + aOffBase + m * 1024 + (ks ? xk1 : xk0)]);
    };
    auto ldb = [&](int b, int n, int ks) -> bf16x8 {
        return *(const bf16x8*)(&sBp[b * 16384 + bOffBase + n * 1024 + (ks ? xk1 : xk0)]);
    };

    f32x4 acc[8][4];
#pragma unroll
    for (int i = 0; i < 8; ++i)
#pragma unroll
        for (int j = 0; j < 4; ++j) acc[i][j] = (f32x4){0.f, 0.f, 0.f, 0.f};

    bf16x8 af00, af01, af10, af11;
    bf16x8 bf00, bf01, bf10, bf11, bf20, bf21, bf30, bf31;

    // --- prologue: tile0 (buf0) fully, tile1 (buf1) B-halves ---
    stageA(0, 0, 0); stageA(0, 0, 1);
    stageB(0, 0, 0); stageB(0, 0, 1);
    stageB(1, 1, 0); stageB(1, 1, 1);
    VMW4;       // tile 0 fully landed; B(1) x2 halves still in flight
    BARR;

    const int niter = K >> 7;   // K/128, two K-tiles per iteration
    for (int i = 0; i < niter; ++i) {
        const bool nlast = (i + 1 < niter);
        const int kO  = 2 * i + 1;
        const int kN  = 2 * i + 2;
        const int kN1 = 2 * i + 3;
        // phases 1-4: compute buf0 (tile 2i)
        PHASE(0, 0, stageA(1, kO, 0), ((void)0));
        PHASE(0, 1, stageA(1, kO, 1), ((void)0));
        PHASE(0, 2, if (nlast) stageB(0, kN, 0), ((void)0));
        PHASE(0, 3, if (nlast) stageB(0, kN, 1),
              if (nlast) { VMW4; } else { VMW0; });
        // phases 5-8: compute buf1 (tile 2i+1)
        PHASE(1, 0, if (nlast) stageA(0, kN, 0), ((void)0));
        PHASE(1, 1, if (nlast) stageA(0, kN, 1), ((void)0));
        PHASE(1, 2, if (nlast) stageB(1, kN1, 0), ((void)0));
        PHASE(1, 3, if (nlast) stageB(1, kN1, 1),
              if (nlast) { VMW4; });
    }

    if (EPI == 0) {
        // --- LDS-staged coalesced bf16 epilogue (gelu). Reuse smem as
        // sC[256][256] bf16 with bank XOR-swizzle (bits [6:5] ^= row>>2).
        bf16_t* sC = (bf16_t*)smem;
#pragma unroll
        for (int n = 0; n < 4; ++n) {
            const int colL = wc * 64 + n * 16 + laneLow;
            const float bv = bias[bn * 256 + colL];
#pragma unroll
            for (int m = 0; m < 8; ++m) {
#pragma unroll
                for (int j = 0; j < 4; ++j) {
                    const int rowL = wr * 128 + m * 16 + (laneHi << 2) + j;
                    float v = acc[m][n][j] + bv;
                    int byte = (rowL << 9) + (colL << 1);
                    byte ^= ((rowL >> 2) & 3) << 5;
                    *(bf16_t*)((char*)sC + byte) = (bf16_t)gelu_f(v);
                }
            }
        }
        LGKM0;
        BARR;
        bf16_t* Cb = (bf16_t*)Cout;
        const size_t rb = (size_t)bm * 256, cb = (size_t)bn * 256;
#pragma unroll
        for (int s = 0; s < 16; ++s) {
            const int row = s * 16 + (tid >> 5);
            int byte = (row << 9) + ((tid & 31) << 4);
            byte ^= ((row >> 2) & 3) << 5;
            bf16x8 v = *(const bf16x8*)((char*)sC + byte);
            *(bf16x8*)(&Cb[(rb + row) * N + cb + ((tid & 31) << 3)]) = v;
        }
    } else {
        // --- direct f32 epilogue (64-B contiguous sectors per quarter-wave) ---
        const int r0 = bm * 256 + wr * 128 + (laneHi << 2);
        const int c0 = bn * 256 + wc * 64 + laneLow;
        float* Cf = (float*)Cout;
#pragma unroll
        for (int n = 0; n < 4; ++n) {
            const int col = c0 + n * 16;
            const float bv = bias[col];
#pragma unroll
            for (int m = 0; m < 8; ++m) {
#pragma unroll
                for (int j = 0; j < 4; ++j) {
                    const int row = r0 + m * 16 + j;
                    Cf[(size_t)row * N + col] = acc[m][n][j] + bv;
                }
            }
        }
    }
}

// ---------------------------------------------------------------------------
extern "C" void kernel_launch(void* const* d_in, const int* in_sizes, int n_in,
                              void* d_out, int out_size, void* d_ws, size_t ws_size,
                              hipStream_t stream) {
    const float* inputs = (const float*)d_in[0];
    const float* up_w   = (const float*)d_in[1];
    const float* up_b   = (const float*)d_in[2];
    const float* dn_w   = (const float*)d_in[3];
    const float* dn_b   = (const float*)d_in[4];
    float* out = (float*)d_out;

    const int D = in_sizes[4];            // 2048
    const int F = in_sizes[2];            // 8192
    const int M = in_sizes[0] / D;        // 8192 (B*S)

    // workspace layout (region0 reused: in_bf16 for GEMM1, then w_dn^T)
    size_t r0_bytes = (size_t)(M > F ? M : F) * D * 2;
    char* ws = (char*)d_ws;
    bf16_t* in_bf = (bf16_t*)ws;                          // M x D
    bf16_t* wdn_t = (bf16_t*)ws;                          // D x F (after GEMM1)
    bf16_t* wup_t = (bf16_t*)(ws + r0_bytes);             // F x D
    bf16_t* mid   = (bf16_t*)(ws + r0_bytes + (size_t)F * D * 2);  // M x F

    // 1) inputs -> bf16
    int ncvt = M * D;
    cvt_kernel<<<(ncvt / 8 + 255) / 256, 256, 0, stream>>>(inputs, in_bf, ncvt);
    // 2) quantize+dequant up weights -> bf16, transposed (F x D)
    int qup = (D / 32) * F;
    quantize_kernel<<<(qup + 255) / 256, 256, 0, stream>>>(up_w, wup_t, D, F);
    // 3) GEMM1: mid = gelu(in @ W_up + b_up)   [M x F, bf16]  (32x32 tile grid)
    gemm_kernel<0, 1><<<(M / 256) * (F / 256), 512, 0, stream>>>(
        in_bf, wup_t, up_b, (void*)mid, M, F, D);
    // 4) quantize+dequant down weights -> bf16, transposed (D x F); reuses region0
    int qdn = (F / 32) * D;
    quantize_kernel<<<(qdn + 255) / 256, 256, 0, stream>>>(dn_w, wdn_t, F, D);
    // 5) GEMM2: out = mid @ W_dn + b_dn        [M x D, fp32]
    gemm_kernel<1, 0><<<(M / 256) * (D / 256), 512, 0, stream>>>(
        mid, wdn_t, dn_b, (void*)out, M, D, F);
}